// Round 1
// baseline (2627.580 us; speedup 1.0000x reference)
//
#include <hip/hip_runtime.h>
#include <hip/hip_bf16.h>

#define NB 64
#define NT 25
#define NS 50
#define EMBD 300
#define NFILT 100
#define HD 256
#define NOUT 31
#define NBT (NB*NT)

__device__ __forceinline__ float hsum4(float4 a) { return (a.x + a.y) + (a.z + a.w); }
__device__ __forceinline__ void fma4(float4& a, float4 w, float4 x) {
    a.x = fmaf(w.x, x.x, a.x); a.y = fmaf(w.y, x.y, a.y);
    a.z = fmaf(w.z, x.z, a.z); a.w = fmaf(w.w, x.w, a.w);
}
__device__ __forceinline__ float sigmoidf_(float x) { return 1.0f / (1.0f + __expf(-x)); }

// ---------------- conv: per-sample WG, x in LDS, relu+max via int-punned atomicMax ----
template<int FS>
__device__ __forceinline__ void conv_fs(const float* __restrict__ xs, int* __restrict__ fmx,
    const float* __restrict__ W, const float* __restrict__ bias, int tid)
{
    constexpr int P = NS - FS + 1;        // valid positions
    constexpr int Ph = (P + 1) / 2;       // position pairs (p, p+Ph)
    constexpr int K4 = FS * EMBD / 4;
    constexpr int NTASK = (NFILT / 2) * Ph;
    for (int task = tid; task < NTASK; task += 256) {
        const int fp = task / Ph;
        const int pp = task - fp * Ph;
        const int f0 = fp * 2;
        const int p0 = pp;
        const int p1 = pp + Ph;
        const bool has2 = (p1 < P);
        const float4* w0 = (const float4*)(W + (size_t)f0 * (FS * EMBD));
        const float4* w1 = (const float4*)(W + (size_t)(f0 + 1) * (FS * EMBD));
        const float4* x0 = (const float4*)(xs + p0 * EMBD);
        const float4* x1 = (const float4*)(xs + (has2 ? p1 : p0) * EMBD);
        float4 a00{0,0,0,0}, a01{0,0,0,0}, a10{0,0,0,0}, a11{0,0,0,0};
        for (int k = 0; k < K4; ++k) {
            float4 wa = w0[k];
            float4 wb = w1[k];
            float4 xa = x0[k];
            float4 xb = x1[k];
            fma4(a00, wa, xa); fma4(a01, wa, xb);
            fma4(a10, wb, xa); fma4(a11, wb, xb);
        }
        const float bb0 = bias[f0], bb1 = bias[f0 + 1];
        atomicMax(&fmx[f0],     __float_as_int(hsum4(a00) + bb0));
        atomicMax(&fmx[f0 + 1], __float_as_int(hsum4(a10) + bb1));
        if (has2) {
            atomicMax(&fmx[f0],     __float_as_int(hsum4(a01) + bb0));
            atomicMax(&fmx[f0 + 1], __float_as_int(hsum4(a11) + bb1));
        }
    }
}

__global__ __launch_bounds__(256) void k_conv(
    const int* __restrict__ tok, const float* __restrict__ emb,
    const float* __restrict__ w3, const float* __restrict__ b3,
    const float* __restrict__ w4, const float* __restrict__ b4,
    const float* __restrict__ w5, const float* __restrict__ b5,
    float* __restrict__ rin)
{
    __shared__ float xs[NS * EMBD];   // 60000 B
    __shared__ int fmx[3 * NFILT];
    const int bt = blockIdx.x;
    const int tid = threadIdx.x;
    const int* tk = tok + bt * NS;
    for (int i4 = tid; i4 < NS * EMBD / 4; i4 += 256) {
        const int s = i4 / (EMBD / 4);
        const int e4 = i4 - s * (EMBD / 4);
        const int t = tk[s];
        ((float4*)xs)[i4] = ((const float4*)(emb + (size_t)t * EMBD))[e4];
    }
    for (int i = tid; i < 3 * NFILT; i += 256) fmx[i] = 0;  // relu floor: max(0,·)
    __syncthreads();
    conv_fs<3>(xs, fmx,             w3, b3, tid);
    conv_fs<4>(xs, fmx + NFILT,     w4, b4, tid);
    conv_fs<5>(xs, fmx + 2 * NFILT, w5, b5, tid);
    __syncthreads();
    for (int i = tid; i < 3 * NFILT; i += 256)
        rin[(size_t)bt * (3 * NFILT) + i] = __int_as_float(fmx[i]);
}

// ---------------- input-gate GEMM: gin[d][bt][g] = rin[bt]·wih_d[g] + bih_d[g]+bhh_d[g]
__global__ __launch_bounds__(256) void k_gin(
    const float* __restrict__ rin,
    const float* __restrict__ wih,   const float* __restrict__ bih,   const float* __restrict__ bhh,
    const float* __restrict__ wih_r, const float* __restrict__ bih_r, const float* __restrict__ bhh_r,
    float* __restrict__ gin)
{
    __shared__ float xsh[8 * EMBD];
    const int bt0 = blockIdx.x * 8;
    const int tid = threadIdx.x;
    const float4* src = (const float4*)(rin + (size_t)bt0 * EMBD);
    for (int i4 = tid; i4 < 8 * EMBD / 4; i4 += 256) ((float4*)xsh)[i4] = src[i4];
    __syncthreads();
    for (int g2 = tid; g2 < 2 * 1024; g2 += 256) {
        const int d = g2 >> 10;
        const int g = g2 & 1023;
        const float* wp = (d ? wih_r : wih) + (size_t)g * EMBD;
        const float bb = d ? (bih_r[g] + bhh_r[g]) : (bih[g] + bhh[g]);
        const float4* w4p = (const float4*)wp;
        float4 acc[8];
        #pragma unroll
        for (int r = 0; r < 8; ++r) acc[r] = {0,0,0,0};
        for (int k = 0; k < EMBD / 4; ++k) {
            const float4 wv = w4p[k];
            #pragma unroll
            for (int r = 0; r < 8; ++r) fma4(acc[r], wv, ((const float4*)(xsh + r * EMBD))[k]);
        }
        #pragma unroll
        for (int r = 0; r < 8; ++r)
            gin[((size_t)d * NBT + bt0 + r) * 1024 + g] = hsum4(acc[r]) + bb;
    }
}

// ---------------- recurrence: one WG per (dir, batch); h in LDS, c in regs ----
__global__ __launch_bounds__(256) void k_lstm(
    const float* __restrict__ gin,
    const float* __restrict__ whh, const float* __restrict__ whh_r,
    float* __restrict__ hs)
{
    const int dir = blockIdx.x >> 6;   // 0 = rev (uses whh), 1 = fwd (uses whh_r)
    const int b = blockIdx.x & 63;
    const float* W = dir ? whh_r : whh;
    const float* gb = gin + ((size_t)dir * NBT + b * NT) * 1024;
    float* hb = hs + ((size_t)dir * NBT + b * NT) * HD;
    __shared__ float hsh[HD];
    const int j = threadIdx.x;
    hsh[j] = 0.0f;
    float c = 0.0f;
    const float4* wi4 = (const float4*)(W + (size_t)j * HD);
    const float4* wf4 = (const float4*)(W + (size_t)(HD + j) * HD);
    const float4* wg4 = (const float4*)(W + (size_t)(2 * HD + j) * HD);
    const float4* wo4 = (const float4*)(W + (size_t)(3 * HD + j) * HD);
    __syncthreads();
    for (int ti = 0; ti < NT; ++ti) {
        const int t = dir ? ti : (NT - 1 - ti);
        const float* g = gb + (size_t)t * 1024;
        float4 ai{0,0,0,0}, af{0,0,0,0}, ag{0,0,0,0}, ao{0,0,0,0};
        for (int k = 0; k < HD / 4; ++k) {
            const float4 h4 = ((const float4*)hsh)[k];
            fma4(ai, wi4[k], h4);
            fma4(af, wf4[k], h4);
            fma4(ag, wg4[k], h4);
            fma4(ao, wo4[k], h4);
        }
        const float gi = hsum4(ai) + g[j];
        const float gf = hsum4(af) + g[HD + j];
        const float gg = hsum4(ag) + g[2 * HD + j];
        const float go = hsum4(ao) + g[3 * HD + j];
        c = sigmoidf_(gf) * c + sigmoidf_(gi) * tanhf(gg);
        const float hn = sigmoidf_(go) * tanhf(c);
        __syncthreads();
        hsh[j] = hn;
        hb[(size_t)t * HD + j] = hn;
        __syncthreads();
    }
}

// ---------------- output projection + sigmoid ----
__global__ __launch_bounds__(64) void k_out(
    const float* __restrict__ hs, const float* __restrict__ w, const float* __restrict__ bias,
    float* __restrict__ out)
{
    __shared__ float hsh[2 * HD];
    const int bt = blockIdx.x;
    const int tid = threadIdx.x;
    const float4* rev4 = (const float4*)(hs + (size_t)bt * HD);
    const float4* fwd4 = (const float4*)(hs + ((size_t)NBT + bt) * HD);
    for (int i = tid; i < 2 * HD / 4; i += 64)
        ((float4*)hsh)[i] = (i < HD / 4) ? rev4[i] : fwd4[i - HD / 4];
    __syncthreads();
    if (tid < NOUT) {
        const float4* wr = (const float4*)(w + (size_t)tid * (2 * HD));
        float4 acc{0,0,0,0};
        for (int k = 0; k < 2 * HD / 4; ++k) fma4(acc, wr[k], ((const float4*)hsh)[k]);
        out[(size_t)bt * NOUT + tid] = sigmoidf_(hsum4(acc) + bias[tid]);
    }
}

extern "C" void kernel_launch(void* const* d_in, const int* in_sizes, int n_in,
                              void* d_out, int out_size, void* d_ws, size_t ws_size,
                              hipStream_t stream)
{
    const int*   tok   = (const int*)d_in[0];
    const float* emb   = (const float*)d_in[1];
    const float* w3    = (const float*)d_in[2];
    const float* b3    = (const float*)d_in[3];
    const float* w4    = (const float*)d_in[4];
    const float* b4    = (const float*)d_in[5];
    const float* w5    = (const float*)d_in[6];
    const float* b5    = (const float*)d_in[7];
    const float* wih   = (const float*)d_in[8];
    const float* whh   = (const float*)d_in[9];
    const float* bih   = (const float*)d_in[10];
    const float* bhh   = (const float*)d_in[11];
    const float* wih_r = (const float*)d_in[12];
    const float* whh_r = (const float*)d_in[13];
    const float* bih_r = (const float*)d_in[14];
    const float* bhh_r = (const float*)d_in[15];
    const float* h2o_w = (const float*)d_in[16];
    const float* h2o_b = (const float*)d_in[17];

    float* ws  = (float*)d_ws;
    float* rin = ws;                                  // 1600*300        = 480,000 f
    float* gin = rin + (size_t)NBT * 3 * NFILT;       // 2*1600*1024    = 3,276,800 f
    float* hs  = gin + (size_t)2 * NBT * 1024;        // 2*1600*256     = 819,200 f

    k_conv<<<NBT, 256, 0, stream>>>(tok, emb, w3, b3, w4, b4, w5, b5, rin);
    k_gin <<<NBT / 8, 256, 0, stream>>>(rin, wih, bih, bhh, wih_r, bih_r, bhh_r, gin);
    k_lstm<<<2 * NB, 256, 0, stream>>>(gin, whh, whh_r, hs);
    k_out <<<NBT, 64, 0, stream>>>(hs, h2o_w, h2o_b, (float*)d_out);
}

// Round 2
// 1156.660 us; speedup vs baseline: 2.2717x; 2.2717x over previous
//
#include <hip/hip_runtime.h>
#include <hip/hip_bf16.h>

#define NB 64
#define NT 25
#define NS 50
#define EMBD 300
#define NFILT 100
#define HD 256
#define NOUT 31
#define NBT (NB*NT)

#define KP3 928
#define KP4 1216
#define KP5 1504
#define XS_LEN 15104   // 50*300 = 15000 + pad (max read 45*300+1504 = 15004)

typedef __attribute__((ext_vector_type(8))) short short8;
typedef __attribute__((ext_vector_type(4))) float f32x4;

__device__ __forceinline__ float hsum4(float4 a) { return (a.x + a.y) + (a.z + a.w); }
__device__ __forceinline__ void fma4(float4& a, float4 w, float4 x) {
    a.x = fmaf(w.x, x.x, a.x); a.y = fmaf(w.y, x.y, a.y);
    a.z = fmaf(w.z, x.z, a.z); a.w = fmaf(w.w, x.w, a.w);
}
__device__ __forceinline__ float sigmoidf_(float x) { return 1.0f / (1.0f + __expf(-x)); }

__device__ __forceinline__ unsigned short f2bf(float f) {
    union { float f; unsigned u; } v; v.f = f;
    unsigned r = v.u + 0x7FFF + ((v.u >> 16) & 1);   // RNE
    return (unsigned short)(r >> 16);
}

// 8 bf16 from an 8-byte-aligned LDS address (rows have odd*600B bases → not 16B aligned)
__device__ __forceinline__ short8 ld8_a8(const unsigned short* p) {
    short8 r;
    ((uint2*)&r)[0] = *(const uint2*)p;
    ((uint2*)&r)[1] = *(const uint2*)(p + 4);
    return r;
}

// ---------------- weight prep: f32 conv weights -> bf16, K padded to 32-mult, F padded to 112
__global__ __launch_bounds__(256) void k_prep(
    const float* __restrict__ w3, const float* __restrict__ w4, const float* __restrict__ w5,
    unsigned short* __restrict__ wb)
{
    const int S0 = 112 * KP3, S1 = S0 + 112 * KP4, S2 = S1 + 112 * KP5;
    int idx = blockIdx.x * 256 + threadIdx.x;
    if (idx >= S2) return;
    int rel, Kp, K; const float* src;
    if (idx < S0)      { rel = idx;      Kp = KP3; K = 900;  src = w3; }
    else if (idx < S1) { rel = idx - S0; Kp = KP4; K = 1200; src = w4; }
    else               { rel = idx - S1; Kp = KP5; K = 1500; src = w5; }
    int f = rel / Kp, k = rel - f * Kp;
    float v = (f < NFILT && k < K) ? src[(size_t)f * K + k] : 0.0f;
    wb[idx] = f2bf(v);
}

// ---------------- conv: per-sample WG; im2col GEMM via MFMA 16x16x32 bf16 ----
// A[p][k] = xs[p*300 + k] (overlapping windows), B[k][f] = wb[f][k] (zero-padded)
__global__ __launch_bounds__(256) void k_conv(
    const int* __restrict__ tok, const float* __restrict__ emb,
    const unsigned short* __restrict__ wb,
    const float* __restrict__ b3, const float* __restrict__ b4, const float* __restrict__ b5,
    float* __restrict__ rin)
{
    __shared__ unsigned short xs[XS_LEN];
    const int bt = blockIdx.x;
    const int tid = threadIdx.x;
    const int* tk = tok + bt * NS;
    // gather emb rows, convert f32->bf16 into packed [50][300]
    for (int i4 = tid; i4 < NS * (EMBD / 4); i4 += 256) {
        const int s = i4 / 75, e4 = i4 - s * 75;
        float4 v = ((const float4*)(emb + (size_t)tk[s] * EMBD))[e4];
        unsigned short o0 = f2bf(v.x), o1 = f2bf(v.y), o2 = f2bf(v.z), o3 = f2bf(v.w);
        uint2 pk;
        pk.x = (unsigned)o0 | ((unsigned)o1 << 16);
        pk.y = (unsigned)o2 | ((unsigned)o3 << 16);
        *(uint2*)(xs + s * 300 + e4 * 4) = pk;   // byte addr 600s+8e4, 8B aligned
    }
    for (int i = NS * EMBD + tid; i < XS_LEN; i += 256) xs[i] = 0;  // no NaN garbage past K
    __syncthreads();

    const int wave = tid >> 6, lane = tid & 63;
    const int col = lane & 15, kg = lane >> 4;

    for (int job = wave; job < 21; job += 4) {
        const int fsi = job / 7, ntile = job - fsi * 7;
        int Kp, P, obase; const unsigned short* W; const float* bias;
        if (fsi == 0)      { Kp = KP3; P = 48; W = wb;                       bias = b3; obase = 0; }
        else if (fsi == 1) { Kp = KP4; P = 47; W = wb + 112 * KP3;           bias = b4; obase = NFILT; }
        else               { Kp = KP5; P = 46; W = wb + 112 * (KP3 + KP4);   bias = b5; obase = 2 * NFILT; }

        const unsigned short* wrow = W + (size_t)(ntile * 16 + col) * Kp + kg * 8;
        const unsigned short* xbase = xs + (size_t)(lane & 15) * 300 + kg * 8;
        f32x4 acc0 = {0,0,0,0}, acc1 = {0,0,0,0}, acc2 = {0,0,0,0};

        const int nks = Kp / 32;
        for (int ks = 0; ks < nks; ++ks) {
            const int k0 = ks * 32;
            short8 bfrag = *(const short8*)(wrow + k0);             // global (L2), 16B aligned
            short8 a0 = ld8_a8(xbase + k0);
            short8 a1 = ld8_a8(xbase + 16 * 300 + k0);
            short8 a2 = ld8_a8(xbase + 32 * 300 + k0);
            acc0 = __builtin_amdgcn_mfma_f32_16x16x32_bf16(a0, bfrag, acc0, 0, 0, 0);
            acc1 = __builtin_amdgcn_mfma_f32_16x16x32_bf16(a1, bfrag, acc1, 0, 0, 0);
            acc2 = __builtin_amdgcn_mfma_f32_16x16x32_bf16(a2, bfrag, acc2, 0, 0, 0);
        }

        // max over valid positions: C row = m*16 + kg*4 + reg, col = lane&15
        float pmax = -1e30f;
        #pragma unroll
        for (int reg = 0; reg < 4; ++reg) {
            pmax = fmaxf(pmax, acc0[reg]);                          // rows 0..15 always valid
            pmax = fmaxf(pmax, acc1[reg]);                          // rows 16..31 always valid
            const int r2 = 32 + kg * 4 + reg;
            if (r2 < P) pmax = fmaxf(pmax, acc2[reg]);
        }
        pmax = fmaxf(pmax, __shfl_xor(pmax, 16, 64));
        pmax = fmaxf(pmax, __shfl_xor(pmax, 32, 64));
        if (lane < 16) {
            const int f = ntile * 16 + lane;
            if (f < NFILT)
                rin[(size_t)bt * (3 * NFILT) + obase + f] = fmaxf(0.0f, pmax + bias[f]);
        }
    }
}

// ---------------- input-gate GEMM (unchanged) ----
__global__ __launch_bounds__(256) void k_gin(
    const float* __restrict__ rin,
    const float* __restrict__ wih,   const float* __restrict__ bih,   const float* __restrict__ bhh,
    const float* __restrict__ wih_r, const float* __restrict__ bih_r, const float* __restrict__ bhh_r,
    float* __restrict__ gin)
{
    __shared__ float xsh[8 * EMBD];
    const int bt0 = blockIdx.x * 8;
    const int tid = threadIdx.x;
    const float4* src = (const float4*)(rin + (size_t)bt0 * EMBD);
    for (int i4 = tid; i4 < 8 * EMBD / 4; i4 += 256) ((float4*)xsh)[i4] = src[i4];
    __syncthreads();
    for (int g2 = tid; g2 < 2 * 1024; g2 += 256) {
        const int d = g2 >> 10;
        const int g = g2 & 1023;
        const float* wp = (d ? wih_r : wih) + (size_t)g * EMBD;
        const float bb = d ? (bih_r[g] + bhh_r[g]) : (bih[g] + bhh[g]);
        const float4* w4p = (const float4*)wp;
        float4 acc[8];
        #pragma unroll
        for (int r = 0; r < 8; ++r) acc[r] = {0,0,0,0};
        for (int k = 0; k < EMBD / 4; ++k) {
            const float4 wv = w4p[k];
            #pragma unroll
            for (int r = 0; r < 8; ++r) fma4(acc[r], wv, ((const float4*)(xsh + r * EMBD))[k]);
        }
        #pragma unroll
        for (int r = 0; r < 8; ++r)
            gin[((size_t)d * NBT + bt0 + r) * 1024 + g] = hsum4(acc[r]) + bb;
    }
}

// ---------------- recurrence (unchanged this round) ----
__global__ __launch_bounds__(256) void k_lstm(
    const float* __restrict__ gin,
    const float* __restrict__ whh, const float* __restrict__ whh_r,
    float* __restrict__ hs)
{
    const int dir = blockIdx.x >> 6;
    const int b = blockIdx.x & 63;
    const float* W = dir ? whh_r : whh;
    const float* gb = gin + ((size_t)dir * NBT + b * NT) * 1024;
    float* hb = hs + ((size_t)dir * NBT + b * NT) * HD;
    __shared__ float hsh[HD];
    const int j = threadIdx.x;
    hsh[j] = 0.0f;
    float c = 0.0f;
    const float4* wi4 = (const float4*)(W + (size_t)j * HD);
    const float4* wf4 = (const float4*)(W + (size_t)(HD + j) * HD);
    const float4* wg4 = (const float4*)(W + (size_t)(2 * HD + j) * HD);
    const float4* wo4 = (const float4*)(W + (size_t)(3 * HD + j) * HD);
    __syncthreads();
    for (int ti = 0; ti < NT; ++ti) {
        const int t = dir ? ti : (NT - 1 - ti);
        const float* g = gb + (size_t)t * 1024;
        float4 ai{0,0,0,0}, af{0,0,0,0}, ag{0,0,0,0}, ao{0,0,0,0};
        for (int k = 0; k < HD / 4; ++k) {
            const float4 h4 = ((const float4*)hsh)[k];
            fma4(ai, wi4[k], h4);
            fma4(af, wf4[k], h4);
            fma4(ag, wg4[k], h4);
            fma4(ao, wo4[k], h4);
        }
        const float gi = hsum4(ai) + g[j];
        const float gf = hsum4(af) + g[HD + j];
        const float gg = hsum4(ag) + g[2 * HD + j];
        const float go = hsum4(ao) + g[3 * HD + j];
        c = sigmoidf_(gf) * c + sigmoidf_(gi) * tanhf(gg);
        const float hn = sigmoidf_(go) * tanhf(c);
        __syncthreads();
        hsh[j] = hn;
        hb[(size_t)t * HD + j] = hn;
        __syncthreads();
    }
}

// ---------------- output projection + sigmoid (unchanged) ----
__global__ __launch_bounds__(64) void k_out(
    const float* __restrict__ hs, const float* __restrict__ w, const float* __restrict__ bias,
    float* __restrict__ out)
{
    __shared__ float hsh[2 * HD];
    const int bt = blockIdx.x;
    const int tid = threadIdx.x;
    const float4* rev4 = (const float4*)(hs + (size_t)bt * HD);
    const float4* fwd4 = (const float4*)(hs + ((size_t)NBT + bt) * HD);
    for (int i = tid; i < 2 * HD / 4; i += 64)
        ((float4*)hsh)[i] = (i < HD / 4) ? rev4[i] : fwd4[i - HD / 4];
    __syncthreads();
    if (tid < NOUT) {
        const float4* wr = (const float4*)(w + (size_t)tid * (2 * HD));
        float4 acc{0,0,0,0};
        for (int k = 0; k < 2 * HD / 4; ++k) fma4(acc, wr[k], ((const float4*)hsh)[k]);
        out[(size_t)bt * NOUT + tid] = sigmoidf_(hsum4(acc) + bias[tid]);
    }
}

extern "C" void kernel_launch(void* const* d_in, const int* in_sizes, int n_in,
                              void* d_out, int out_size, void* d_ws, size_t ws_size,
                              hipStream_t stream)
{
    const int*   tok   = (const int*)d_in[0];
    const float* emb   = (const float*)d_in[1];
    const float* w3    = (const float*)d_in[2];
    const float* b3    = (const float*)d_in[3];
    const float* w4    = (const float*)d_in[4];
    const float* b4    = (const float*)d_in[5];
    const float* w5    = (const float*)d_in[6];
    const float* b5    = (const float*)d_in[7];
    const float* wih   = (const float*)d_in[8];
    const float* whh   = (const float*)d_in[9];
    const float* bih   = (const float*)d_in[10];
    const float* bhh   = (const float*)d_in[11];
    const float* wih_r = (const float*)d_in[12];
    const float* whh_r = (const float*)d_in[13];
    const float* bih_r = (const float*)d_in[14];
    const float* bhh_r = (const float*)d_in[15];
    const float* h2o_w = (const float*)d_in[16];
    const float* h2o_b = (const float*)d_in[17];

    float* ws  = (float*)d_ws;
    float* rin = ws;                                  // 1600*300
    float* gin = rin + (size_t)NBT * 3 * NFILT;       // 2*1600*1024
    float* hs  = gin + (size_t)2 * NBT * 1024;        // 2*1600*256
    // bf16 conv weights overlay the gin region (dead until k_gin; stream-ordered)
    unsigned short* wb = (unsigned short*)gin;        // 408,576 bf16 = 817KB << 13.1MB

    k_prep<<<1596, 256, 0, stream>>>(w3, w4, w5, wb);
    k_conv<<<NBT, 256, 0, stream>>>(tok, emb, wb, b3, b4, b5, rin);
    k_gin <<<NBT / 8, 256, 0, stream>>>(rin, wih, bih, bhh, wih_r, bih_r, bhh_r, gin);
    k_lstm<<<2 * NB, 256, 0, stream>>>(gin, whh, whh_r, hs);
    k_out <<<NBT, 64, 0, stream>>>(hs, h2o_w, h2o_b, (float*)d_out);
}

// Round 3
// 587.585 us; speedup vs baseline: 4.4718x; 1.9685x over previous
//
#include <hip/hip_runtime.h>
#include <hip/hip_bf16.h>

#define NB 64
#define NT 25
#define NS 50
#define EMBD 300
#define NFILT 100
#define HD 256
#define NOUT 31
#define NBT (NB*NT)

#define KP3 928
#define KP4 1216
#define KP5 1504
#define XS_LEN 15104   // 50*300 = 15000 + pad (max read 45*300+1504 = 15004)

typedef __attribute__((ext_vector_type(8))) short short8;
typedef __attribute__((ext_vector_type(4))) float f32x4;

__device__ __forceinline__ float hsum4(float4 a) { return (a.x + a.y) + (a.z + a.w); }
__device__ __forceinline__ void fma4(float4& a, float4 w, float4 x) {
    a.x = fmaf(w.x, x.x, a.x); a.y = fmaf(w.y, x.y, a.y);
    a.z = fmaf(w.z, x.z, a.z); a.w = fmaf(w.w, x.w, a.w);
}
__device__ __forceinline__ float sigmoidf_(float x) { return 1.0f / (1.0f + __expf(-x)); }
__device__ __forceinline__ float tanh_fast(float x) {
    x = fminf(fmaxf(x, -15.0f), 15.0f);          // clamp: avoid inf/inf
    const float e = __expf(2.0f * x);
    return (e - 1.0f) / (e + 1.0f);
}

__device__ __forceinline__ unsigned short f2bf(float f) {
    union { float f; unsigned u; } v; v.f = f;
    unsigned r = v.u + 0x7FFF + ((v.u >> 16) & 1);   // RNE
    return (unsigned short)(r >> 16);
}

// 8 bf16 from an 8-byte-aligned LDS address
__device__ __forceinline__ short8 ld8_a8(const unsigned short* p) {
    short8 r;
    ((uint2*)&r)[0] = *(const uint2*)p;
    ((uint2*)&r)[1] = *(const uint2*)(p + 4);
    return r;
}

// ---------------- conv weight prep: f32 -> bf16, K padded to 32-mult, F padded to 112
__global__ __launch_bounds__(256) void k_prep(
    const float* __restrict__ w3, const float* __restrict__ w4, const float* __restrict__ w5,
    unsigned short* __restrict__ wb)
{
    const int S0 = 112 * KP3, S1 = S0 + 112 * KP4, S2 = S1 + 112 * KP5;
    int idx = blockIdx.x * 256 + threadIdx.x;
    if (idx >= S2) return;
    int rel, Kp, K; const float* src;
    if (idx < S0)      { rel = idx;      Kp = KP3; K = 900;  src = w3; }
    else if (idx < S1) { rel = idx - S0; Kp = KP4; K = 1200; src = w4; }
    else               { rel = idx - S1; Kp = KP5; K = 1500; src = w5; }
    int f = rel / Kp, k = rel - f * Kp;
    float v = (f < NFILT && k < K) ? src[(size_t)f * K + k] : 0.0f;
    wb[idx] = f2bf(v);
}

// ---------------- LSTM weight prep: whh/whh_r f32 -> bf16, rows reordered n = j*4+gate
__global__ __launch_bounds__(256) void k_prep2(
    const float* __restrict__ whh, const float* __restrict__ whh_r,
    unsigned short* __restrict__ wb2)
{
    const int idx = blockIdx.x * 256 + threadIdx.x;      // grid = 2048*256 = 524288 exact
    const int dir = idx >> 18;
    const int rem = idx & 262143;
    const int n = rem >> 8, k = rem & 255;
    const int j = n >> 2, gate = n & 3;
    const float* src = dir ? whh_r : whh;
    wb2[idx] = f2bf(src[(size_t)(gate * 256 + j) * 256 + k]);
}

// ---------------- conv: per-sample WG; im2col GEMM via MFMA 16x16x32 bf16 ----
__global__ __launch_bounds__(256) void k_conv(
    const int* __restrict__ tok, const float* __restrict__ emb,
    const unsigned short* __restrict__ wb,
    const float* __restrict__ b3, const float* __restrict__ b4, const float* __restrict__ b5,
    float* __restrict__ rin)
{
    __shared__ unsigned short xs[XS_LEN];
    const int bt = blockIdx.x;
    const int tid = threadIdx.x;
    const int* tk = tok + bt * NS;
    for (int i4 = tid; i4 < NS * (EMBD / 4); i4 += 256) {
        const int s = i4 / 75, e4 = i4 - s * 75;
        float4 v = ((const float4*)(emb + (size_t)tk[s] * EMBD))[e4];
        uint2 pk;
        pk.x = (unsigned)f2bf(v.x) | ((unsigned)f2bf(v.y) << 16);
        pk.y = (unsigned)f2bf(v.z) | ((unsigned)f2bf(v.w) << 16);
        *(uint2*)(xs + s * 300 + e4 * 4) = pk;
    }
    for (int i = NS * EMBD + tid; i < XS_LEN; i += 256) xs[i] = 0;
    __syncthreads();

    const int wave = tid >> 6, lane = tid & 63;
    const int col = lane & 15, kg = lane >> 4;

    for (int job = wave; job < 21; job += 4) {
        const int fsi = job / 7, ntile = job - fsi * 7;
        int Kp, P, obase; const unsigned short* W; const float* bias;
        if (fsi == 0)      { Kp = KP3; P = 48; W = wb;                       bias = b3; obase = 0; }
        else if (fsi == 1) { Kp = KP4; P = 47; W = wb + 112 * KP3;           bias = b4; obase = NFILT; }
        else               { Kp = KP5; P = 46; W = wb + 112 * (KP3 + KP4);   bias = b5; obase = 2 * NFILT; }

        const unsigned short* wrow = W + (size_t)(ntile * 16 + col) * Kp + kg * 8;
        const unsigned short* xbase = xs + (size_t)(lane & 15) * 300 + kg * 8;
        f32x4 acc0 = {0,0,0,0}, acc1 = {0,0,0,0}, acc2 = {0,0,0,0};

        const int nks = Kp / 32;
        for (int ks = 0; ks < nks; ++ks) {
            const int k0 = ks * 32;
            short8 bfrag = *(const short8*)(wrow + k0);
            short8 a0 = ld8_a8(xbase + k0);
            short8 a1 = ld8_a8(xbase + 16 * 300 + k0);
            short8 a2 = ld8_a8(xbase + 32 * 300 + k0);
            acc0 = __builtin_amdgcn_mfma_f32_16x16x32_bf16(a0, bfrag, acc0, 0, 0, 0);
            acc1 = __builtin_amdgcn_mfma_f32_16x16x32_bf16(a1, bfrag, acc1, 0, 0, 0);
            acc2 = __builtin_amdgcn_mfma_f32_16x16x32_bf16(a2, bfrag, acc2, 0, 0, 0);
        }

        float pmax = -1e30f;
        #pragma unroll
        for (int reg = 0; reg < 4; ++reg) {
            pmax = fmaxf(pmax, acc0[reg]);
            pmax = fmaxf(pmax, acc1[reg]);
            const int r2 = 32 + kg * 4 + reg;
            if (r2 < P) pmax = fmaxf(pmax, acc2[reg]);
        }
        pmax = fmaxf(pmax, __shfl_xor(pmax, 16, 64));
        pmax = fmaxf(pmax, __shfl_xor(pmax, 32, 64));
        if (lane < 16) {
            const int f = ntile * 16 + lane;
            if (f < NFILT)
                rin[(size_t)bt * (3 * NFILT) + obase + f] = fmaxf(0.0f, pmax + bias[f]);
        }
    }
}

// ---------------- input-gate GEMM; output reordered g' = (g&255)*4 + (g>>8) ----
__global__ __launch_bounds__(256) void k_gin(
    const float* __restrict__ rin,
    const float* __restrict__ wih,   const float* __restrict__ bih,   const float* __restrict__ bhh,
    const float* __restrict__ wih_r, const float* __restrict__ bih_r, const float* __restrict__ bhh_r,
    float* __restrict__ gin)
{
    __shared__ float xsh[8 * EMBD];
    const int bt0 = blockIdx.x * 8;
    const int tid = threadIdx.x;
    const float4* src = (const float4*)(rin + (size_t)bt0 * EMBD);
    for (int i4 = tid; i4 < 8 * EMBD / 4; i4 += 256) ((float4*)xsh)[i4] = src[i4];
    __syncthreads();
    for (int g2 = tid; g2 < 2 * 1024; g2 += 256) {
        const int d = g2 >> 10;
        const int g = g2 & 1023;
        const float* wp = (d ? wih_r : wih) + (size_t)g * EMBD;
        const float bb = d ? (bih_r[g] + bhh_r[g]) : (bih[g] + bhh[g]);
        const float4* w4p = (const float4*)wp;
        float4 acc[8];
        #pragma unroll
        for (int r = 0; r < 8; ++r) acc[r] = {0,0,0,0};
        for (int k = 0; k < EMBD / 4; ++k) {
            const float4 wv = w4p[k];
            #pragma unroll
            for (int r = 0; r < 8; ++r) fma4(acc[r], wv, ((const float4*)(xsh + r * EMBD))[k]);
        }
        const int gp = ((g & 255) << 2) | (g >> 8);   // j*4 + gate
        #pragma unroll
        for (int r = 0; r < 8; ++r)
            gin[((size_t)d * NBT + bt0 + r) * 1024 + gp] = hsum4(acc[r]) + bb;
    }
}

// ---------------- recurrence: 8 WGs (2 dir x 4 j-slices); W-slice in VGPRs ----
// wb2[dir][n=1024][k=256] bf16, n = j*4+gate. WG (dir,ow) owns n in [ow*256, ow*256+256).
// h exchanged via hglob[dir][2][64][256] f32; spin barrier on cnt[dir].
__global__ __launch_bounds__(256, 1) void k_lstm(
    const float* __restrict__ gin, const unsigned short* __restrict__ wb2,
    float* __restrict__ hglob, unsigned* __restrict__ cnt,
    float* __restrict__ hs)
{
    const int bid = blockIdx.x;
    const int dir = bid >> 2, ow = bid & 3;
    const int tid = threadIdx.x;
    const int wave = tid >> 6, lane = tid & 63;
    const int l15 = lane & 15, kg = lane >> 4;

    __shared__ unsigned short h_lds[64 * 264];   // 33.8 KB, row stride 528B (16B aligned)
    __shared__ float slab[4][1280];              // per-wave recombine scratch [n64][20]

    // B fragments: barr[nt][kk] = W rows n = ow*256 + wave*64 + nt*16 + l15, k = kk*32+kg*8..+8
    const unsigned short* wbase = wb2 + (size_t)dir * (1024 * 256);
    short8 barr[4][8];
#pragma unroll
    for (int nt = 0; nt < 4; ++nt) {
        const int ng = ow * 256 + wave * 64 + nt * 16 + l15;
#pragma unroll
        for (int kk = 0; kk < 8; ++kk)
            barr[nt][kk] = *(const short8*)(wbase + (size_t)ng * 256 + kk * 32 + kg * 8);
    }

    float c[4][4];   // cell state for (b = mt*16+l15, j = (q*4+kg) within wave slice)
#pragma unroll
    for (int mt = 0; mt < 4; ++mt)
#pragma unroll
        for (int q = 0; q < 4; ++q) c[mt][q] = 0.0f;

    float* hg = hglob + (size_t)dir * (2 * 64 * 256);
    unsigned* mycnt = cnt + dir * 64;
    const float* ginb = gin + (size_t)dir * NBT * 1024;
    float* hsb = hs + (size_t)dir * NBT * HD;

    for (int s = 0; s < NT; ++s) {
        const int t = dir ? s : (NT - 1 - s);
        const float* hcur = hg + (s & 1) * (64 * 256);
        float* hnext = hg + ((s + 1) & 1) * (64 * 256);

        // phase 1: stage h_prev (f32 global) -> bf16 LDS [64][264]
#pragma unroll
        for (int r = 0; r < 16; ++r) {
            const int i4 = tid + 256 * r;           // [0,4096)
            const int b = i4 >> 6, k4 = i4 & 63;
            float4 v = ((const float4*)hcur)[i4];
            uint2 pk;
            pk.x = (unsigned)f2bf(v.x) | ((unsigned)f2bf(v.y) << 16);
            pk.y = (unsigned)f2bf(v.z) | ((unsigned)f2bf(v.w) << 16);
            *(uint2*)(h_lds + b * 264 + k4 * 4) = pk;
        }
        __syncthreads();

        // phase 2: G = h x W^T for this WG's 256 n-columns
        f32x4 acc[4][4];
#pragma unroll
        for (int mt = 0; mt < 4; ++mt)
#pragma unroll
            for (int nt = 0; nt < 4; ++nt) acc[mt][nt] = (f32x4){0.f, 0.f, 0.f, 0.f};

#pragma unroll
        for (int kk = 0; kk < 8; ++kk) {
            short8 a[4];
#pragma unroll
            for (int mt = 0; mt < 4; ++mt)
                a[mt] = *(const short8*)(h_lds + (mt * 16 + l15) * 264 + kk * 32 + kg * 8);
#pragma unroll
            for (int mt = 0; mt < 4; ++mt)
#pragma unroll
                for (int nt = 0; nt < 4; ++nt)
                    acc[mt][nt] = __builtin_amdgcn_mfma_f32_16x16x32_bf16(a[mt], barr[nt][kk], acc[mt][nt], 0, 0, 0);
        }

        // phase 3: recombine gates -> c,h (per-wave slab; no inter-wave sync needed)
#pragma unroll
        for (int mt = 0; mt < 4; ++mt) {
#pragma unroll
            for (int nt = 0; nt < 4; ++nt)
                *(f32x4*)(&slab[wave][(nt * 16 + l15) * 20 + kg * 4]) = acc[mt][nt];
#pragma unroll
            for (int q = 0; q < 4; ++q) {
                const int j = q * 4 + kg;                  // [0,16) within wave
                const int jg = ow * 64 + wave * 16 + j;    // [0,256) global hidden idx
                const int bg = mt * 16 + l15;              // batch
                const float gI = slab[wave][(j * 4 + 0) * 20 + l15];
                const float gF = slab[wave][(j * 4 + 1) * 20 + l15];
                const float gG = slab[wave][(j * 4 + 2) * 20 + l15];
                const float gO = slab[wave][(j * 4 + 3) * 20 + l15];
                const float4 gx = *(const float4*)(ginb + (size_t)(bg * NT + t) * 1024 + jg * 4);
                const float vi = sigmoidf_(gI + gx.x);
                const float vf = sigmoidf_(gF + gx.y);
                const float vg = tanh_fast(gG + gx.z);
                const float vo = sigmoidf_(gO + gx.w);
                const float cc = vf * c[mt][q] + vi * vg;
                c[mt][q] = cc;
                const float hh = vo * tanh_fast(cc);
                hnext[bg * 256 + jg] = hh;
                hsb[(size_t)(bg * NT + t) * HD + jg] = hh;
            }
        }

        // phase 4: device-scope barrier across the 4 WGs of this direction
        __threadfence();
        __syncthreads();
        if (tid == 0) {
            atomicAdd(mycnt, 1u);
            const unsigned target = 4u * (unsigned)(s + 1);
            while (atomicAdd(mycnt, 0u) < target) __builtin_amdgcn_s_sleep(8);
        }
        __syncthreads();
        __threadfence();
    }
}

// ---------------- output projection + sigmoid ----
__global__ __launch_bounds__(64) void k_out(
    const float* __restrict__ hs, const float* __restrict__ w, const float* __restrict__ bias,
    float* __restrict__ out)
{
    __shared__ float hsh[2 * HD];
    const int bt = blockIdx.x;
    const int tid = threadIdx.x;
    const float4* rev4 = (const float4*)(hs + (size_t)bt * HD);
    const float4* fwd4 = (const float4*)(hs + ((size_t)NBT + bt) * HD);
    for (int i = tid; i < 2 * HD / 4; i += 64)
        ((float4*)hsh)[i] = (i < HD / 4) ? rev4[i] : fwd4[i - HD / 4];
    __syncthreads();
    if (tid < NOUT) {
        const float4* wr = (const float4*)(w + (size_t)tid * (2 * HD));
        float4 acc{0,0,0,0};
        for (int k = 0; k < 2 * HD / 4; ++k) fma4(acc, wr[k], ((const float4*)hsh)[k]);
        out[(size_t)bt * NOUT + tid] = sigmoidf_(hsum4(acc) + bias[tid]);
    }
}

extern "C" void kernel_launch(void* const* d_in, const int* in_sizes, int n_in,
                              void* d_out, int out_size, void* d_ws, size_t ws_size,
                              hipStream_t stream)
{
    const int*   tok   = (const int*)d_in[0];
    const float* emb   = (const float*)d_in[1];
    const float* w3    = (const float*)d_in[2];
    const float* b3    = (const float*)d_in[3];
    const float* w4    = (const float*)d_in[4];
    const float* b4    = (const float*)d_in[5];
    const float* w5    = (const float*)d_in[6];
    const float* b5    = (const float*)d_in[7];
    const float* wih   = (const float*)d_in[8];
    const float* whh   = (const float*)d_in[9];
    const float* bih   = (const float*)d_in[10];
    const float* bhh   = (const float*)d_in[11];
    const float* wih_r = (const float*)d_in[12];
    const float* whh_r = (const float*)d_in[13];
    const float* bih_r = (const float*)d_in[14];
    const float* bhh_r = (const float*)d_in[15];
    const float* h2o_w = (const float*)d_in[16];
    const float* h2o_b = (const float*)d_in[17];

    float* ws  = (float*)d_ws;
    float* rin = ws;                                  // 480,000 f (dead after k_gin)
    float* gin = rin + (size_t)NBT * 3 * NFILT;       // 3,276,800 f
    float* hs  = gin + (size_t)2 * NBT * 1024;        // 819,200 f
    // conv bf16 weights overlay gin (dead until k_gin writes it)
    unsigned short* wb = (unsigned short*)gin;
    // LSTM-phase buffers overlay rin (dead after k_gin reads it):
    unsigned short* wb2   = (unsigned short*)rin;     // 524,288 ush = 262,144 f
    float*          hglob = rin + 262144;             // 65,536 f
    unsigned*       cnt   = (unsigned*)(rin + 262144 + 65536);   // 128 u32

    k_prep <<<1596, 256, 0, stream>>>(w3, w4, w5, wb);
    k_conv <<<NBT, 256, 0, stream>>>(tok, emb, wb, b3, b4, b5, rin);
    k_gin  <<<NBT / 8, 256, 0, stream>>>(rin, wih, bih, bhh, wih_r, bih_r, bhh_r, gin);
    hipMemsetAsync(hglob, 0, (65536 + 128) * sizeof(float), stream);   // h0 = 0, cnt = 0
    k_prep2<<<2048, 256, 0, stream>>>(whh, whh_r, wb2);
    k_lstm <<<8, 256, 0, stream>>>(gin, wb2, hglob, cnt, hs);
    k_out  <<<NBT, 64, 0, stream>>>(hs, h2o_w, h2o_b, (float*)d_out);
}